// Round 21
// baseline (108.086 us; speedup 1.0000x reference)
//
#include <hip/hip_runtime.h>
#include <hip/hip_bf16.h>

#define HID 512
#define BATCH 2048

typedef __bf16 bf16x8 __attribute__((ext_vector_type(8)));
typedef float f32x4 __attribute__((ext_vector_type(4)));
typedef float f32x16 __attribute__((ext_vector_type(16)));
typedef unsigned short u16x4 __attribute__((ext_vector_type(4)));
typedef __hip_bfloat16 bf16;

__device__ inline unsigned short f2bf(float x) {
    bf16 h = __float2bfloat16(x);
    return __builtin_bit_cast(unsigned short, h);
}
__device__ inline float bf2f(unsigned short u) {
    return __bfloat162float(__builtin_bit_cast(bf16, u));
}

__device__ inline void gload16(const void* g, void* l) {
    __builtin_amdgcn_global_load_lds((const __attribute__((address_space(1))) void*)g,
                                     (__attribute__((address_space(3))) void*)l, 16, 0, 0);
}

// non-temporal 8B store of 4 u16 (producer->consumer buffers cross XCDs; avoid dirty-L2 retention)
__device__ inline void nts4(unsigned short* p, u16x4 v) {
    __builtin_nontemporal_store(v, (u16x4*)p);
}

// ---------------- prep: weight hi/lo split (s2, m1, m3) + layer-0 rank-2 GEMV ----------------
struct CvtArgs { const float* src[7]; };   // s2_W, m1 q/k/v, m3 q/k/v

__global__ void k_prep(CvtArgs a, unsigned short* __restrict__ hi, unsigned short* __restrict__ lo,
                       const float* __restrict__ s0W, const float* __restrict__ s0b,
                       const float* __restrict__ ipw, const float* __restrict__ ipb,
                       float* __restrict__ uV, float* __restrict__ uT, float* __restrict__ uC) {
    const int bid = blockIdx.x;
    if (bid < 2560) {   // cvt: 2,621,440 elems / 4 / 256
        int idx4 = (bid * 256 + threadIdx.x) << 2;
        int seg, off; size_t dst;
        if (idx4 < 1048576) { seg = 0; off = idx4; dst = 1048576 + idx4; }          // s2_W
        else { int r = idx4 - 1048576; seg = 1 + (r >> 18); off = r & 262143; dst = 2097152 + r; }
        f32x4 w = *(const f32x4*)(a.src[seg] + off);
        u16x4 h, l;
        h.x = f2bf(w[0]); h.y = f2bf(w[1]); h.z = f2bf(w[2]); h.w = f2bf(w[3]);
        l.x = f2bf(w[0] - bf2f(h.x)); l.y = f2bf(w[1] - bf2f(h.y));
        l.z = f2bf(w[2] - bf2f(h.z)); l.w = f2bf(w[3] - bf2f(h.w));
        nts4(hi + dst, h);
        nts4(lo + dst, l);
    } else {            // GEMV: 1536 gate rows (skip f-rows 512-1023), 4 waves/block
        const int w = threadIdx.x >> 6, lane = threadIdx.x & 63;
        const int r = (bid - 2560) * 4 + w;            // compact row 0..1535
        const int wr = r < 512 ? r : r + 512;          // W row (i / g / o segments)
        const float* Wp = s0W + (size_t)wr * HID + lane * 8;
        f32x4 wa = *(const f32x4*)Wp, wb = *(const f32x4*)(Wp + 4);
        const float* pw = ipw + lane * 16;             // [HID][2] interleaved
        f32x4 e0 = *(const f32x4*)pw,       e1 = *(const f32x4*)(pw + 4);
        f32x4 e2 = *(const f32x4*)(pw + 8), e3 = *(const f32x4*)(pw + 12);
        f32x4 ba = *(const f32x4*)(ipb + lane * 8), bb = *(const f32x4*)(ipb + lane * 8 + 4);
        float s0 = wa[0]*e0[0] + wa[1]*e0[2] + wa[2]*e1[0] + wa[3]*e1[2]
                 + wb[0]*e2[0] + wb[1]*e2[2] + wb[2]*e3[0] + wb[3]*e3[2];
        float s1 = wa[0]*e0[1] + wa[1]*e0[3] + wa[2]*e1[1] + wa[3]*e1[3]
                 + wb[0]*e2[1] + wb[1]*e2[3] + wb[2]*e3[1] + wb[3]*e3[3];
        float s2 = wa[0]*ba[0] + wa[1]*ba[1] + wa[2]*ba[2] + wa[3]*ba[3]
                 + wb[0]*bb[0] + wb[1]*bb[1] + wb[2]*bb[2] + wb[3]*bb[3];
#pragma unroll
        for (int off = 32; off; off >>= 1) {
            s0 += __shfl_xor(s0, off); s1 += __shfl_xor(s1, off); s2 += __shfl_xor(s2, off);
        }
        if (lane == 0) { uV[r] = s0; uT[r] = s1; uC[r] = s2 + s0b[wr]; }
    }
}

// ---------------- layer-0 sLSTM: gates from rank-2 GEMV result, fused activation ----------------
__global__ void k_slstm0(const float* __restrict__ V, const float* __restrict__ t,
                         const float* __restrict__ uV, const float* __restrict__ uT,
                         const float* __restrict__ uC,
                         unsigned short* __restrict__ hhi, unsigned short* __restrict__ hlo) {
    int idx = blockIdx.x * blockDim.x + threadIdx.x;   // B*HID/4
    int b = idx >> 7, j4 = (idx & 127) << 2;
    float vv = V[b], tt = t[b];
    f32x4 gi = vv * *(const f32x4*)(uV + j4)        + tt * *(const f32x4*)(uT + j4)        + *(const f32x4*)(uC + j4);
    f32x4 gg = vv * *(const f32x4*)(uV + 512 + j4)  + tt * *(const f32x4*)(uT + 512 + j4)  + *(const f32x4*)(uC + 512 + j4);
    f32x4 go = vv * *(const f32x4*)(uV + 1024 + j4) + tt * *(const f32x4*)(uT + 1024 + j4) + *(const f32x4*)(uC + 1024 + j4);
    u16x4 h, l;
    float x[4];
#pragma unroll
    for (int u = 0; u < 4; ++u)
        x[u] = tanhf(expf(gi[u]) * tanhf(gg[u])) / (1.f + expf(-go[u]));
    h.x = f2bf(x[0]); h.y = f2bf(x[1]); h.z = f2bf(x[2]); h.w = f2bf(x[3]);
    l.x = f2bf(x[0] - bf2f(h.x)); l.y = f2bf(x[1] - bf2f(h.y));
    l.z = f2bf(x[2] - bf2f(h.z)); l.w = f2bf(x[3] - bf2f(h.w));
    size_t o = (size_t)b * HID + j4;
    nts4(hhi + o, h);
    nts4(hlo + o, l);
}

// ---------------- native-K split-bf16 GEMM: BK=32, 16 steps, 3-buffer pipeline ----------------
__global__ __launch_bounds__(256) void k_gemm(
    const bf16* __restrict__ Ahi, const bf16* __restrict__ Alo,
    const bf16* __restrict__ Wh0, const bf16* __restrict__ Wh1, const bf16* __restrict__ Wh2,
    const bf16* __restrict__ Wl0, const bf16* __restrict__ Wl1, const bf16* __restrict__ Wl2,
    float* __restrict__ C)
{
    __shared__ __align__(16) bf16 lds[3][16384];   // 96 KB
    const int tid = threadIdx.x, w = tid >> 6, lane = tid & 63;

    const int bid = blockIdx.x;                   // 192 blocks: 8 XCD x 24 slots
    const int xcd = bid & 7, slot = bid >> 3;
    const int m0 = (xcd * 2 + slot / 12) * 128;
    const int n0 = (slot % 12) * 128;
    const int nseg = n0 >> 9, nloc = n0 & 511;
    const bf16* Wh = nseg == 0 ? Wh0 : (nseg == 1 ? Wh1 : Wh2);
    const bf16* Wl = nseg == 0 ? Wl0 : (nseg == 1 ? Wl1 : Wl2);

    const bf16* msrc = (w == 0) ? Ahi : (w == 1) ? Alo : (w == 2) ? Wh : Wl;
    const int rowbase = (w < 2) ? m0 : nloc;
    const size_t srow = (size_t)(rowbase + (lane & 31)) * HID + ((lane >> 5) << 3);

    auto STAGE = [&](int t) {
        bf16* db = &lds[t % 3][0] + (w << 12) + (lane << 3);   // chunk base (m=w, rb=0, ks=0)
        const bf16* gp = msrc + srow + (t << 5);
#pragma unroll
        for (int rb = 0; rb < 4; ++rb)
#pragma unroll
            for (int ks = 0; ks < 2; ++ks)
                gload16(gp + (size_t)(rb << 5) * HID + (ks << 4),
                        db + (((rb << 1) + ks) << 9));
    };

    const int wm = w >> 1, wn = w & 1;
    const int la = lane << 3;
    f32x16 acc00 = {}, acc01 = {}, acc10 = {}, acc11 = {};

    STAGE(0);
    STAGE(1);
    for (int t = 0; t < 16; ++t) {
        if (t < 15)
            asm volatile("s_waitcnt vmcnt(8) lgkmcnt(0)\n\ts_barrier" ::: "memory");
        else
            asm volatile("s_waitcnt vmcnt(0) lgkmcnt(0)\n\ts_barrier" ::: "memory");
        if (t < 14) STAGE(t + 2);   // writes buf (t+2)%3 = (t-1)%3: reads drained above
        const bf16* lb = &lds[t % 3][0];
#pragma unroll
        for (int ks = 0; ks < 2; ++ks) {
            bf16x8 ah0 = *(const bf16x8*)(lb + ((((2*wm    ) << 1) + ks) << 9) + la);
            bf16x8 ah1 = *(const bf16x8*)(lb + ((((2*wm + 1) << 1) + ks) << 9) + la);
            bf16x8 al0 = *(const bf16x8*)(lb + ((8 + ((2*wm    ) << 1) + ks) << 9) + la);
            bf16x8 al1 = *(const bf16x8*)(lb + ((8 + ((2*wm + 1) << 1) + ks) << 9) + la);
            bf16x8 wh0 = *(const bf16x8*)(lb + ((16 + ((2*wn    ) << 1) + ks) << 9) + la);
            bf16x8 wh1 = *(const bf16x8*)(lb + ((16 + ((2*wn + 1) << 1) + ks) << 9) + la);
            bf16x8 wl0 = *(const bf16x8*)(lb + ((24 + ((2*wn    ) << 1) + ks) << 9) + la);
            bf16x8 wl1 = *(const bf16x8*)(lb + ((24 + ((2*wn + 1) << 1) + ks) << 9) + la);
            __builtin_amdgcn_s_setprio(1);
            acc00 = __builtin_amdgcn_mfma_f32_32x32x16_bf16(ah0, wh0, acc00, 0, 0, 0);
            acc01 = __builtin_amdgcn_mfma_f32_32x32x16_bf16(ah0, wh1, acc01, 0, 0, 0);
            acc10 = __builtin_amdgcn_mfma_f32_32x32x16_bf16(ah1, wh0, acc10, 0, 0, 0);
            acc11 = __builtin_amdgcn_mfma_f32_32x32x16_bf16(ah1, wh1, acc11, 0, 0, 0);
            acc00 = __builtin_amdgcn_mfma_f32_32x32x16_bf16(al0, wh0, acc00, 0, 0, 0);
            acc01 = __builtin_amdgcn_mfma_f32_32x32x16_bf16(al0, wh1, acc01, 0, 0, 0);
            acc10 = __builtin_amdgcn_mfma_f32_32x32x16_bf16(al1, wh0, acc10, 0, 0, 0);
            acc11 = __builtin_amdgcn_mfma_f32_32x32x16_bf16(al1, wh1, acc11, 0, 0, 0);
            acc00 = __builtin_amdgcn_mfma_f32_32x32x16_bf16(ah0, wl0, acc00, 0, 0, 0);
            acc01 = __builtin_amdgcn_mfma_f32_32x32x16_bf16(ah0, wl1, acc01, 0, 0, 0);
            acc10 = __builtin_amdgcn_mfma_f32_32x32x16_bf16(ah1, wl0, acc10, 0, 0, 0);
            acc11 = __builtin_amdgcn_mfma_f32_32x32x16_bf16(ah1, wl1, acc11, 0, 0, 0);
            __builtin_amdgcn_s_setprio(0);
        }
    }

    // epilogue: D layout col = lane&31, row = (rr&3) + 8*(rr>>2) + 4*(lane>>5); NT stores
    const f32x16* accs[2][2] = { { &acc00, &acc01 }, { &acc10, &acc11 } };
#pragma unroll
    for (int fi = 0; fi < 2; ++fi)
#pragma unroll
        for (int fj = 0; fj < 2; ++fj) {
            const f32x16& ac = *accs[fi][fj];
            const int col = n0 + ((2 * wn + fj) << 5) + (lane & 31);
            const int rbase = m0 + ((2 * wm + fi) << 5) + ((lane >> 5) << 2);
#pragma unroll
            for (int rr = 0; rr < 16; ++rr) {
                int row = rbase + (rr & 3) + ((rr >> 2) << 3);
                __builtin_nontemporal_store(ac[rr], &C[(size_t)row * 1536 + col]);
            }
        }
}

// ---------------- sLSTM activation (layer 2): + bias, h = sigm(o)*tanh(exp(i)*tanh(g)) ----------------
__global__ void k_slstm_act(const float* __restrict__ g, const float* __restrict__ bp,
                            unsigned short* __restrict__ hhi, unsigned short* __restrict__ hlo) {
    int idx = blockIdx.x * blockDim.x + threadIdx.x;
    int b = idx >> 7, j4 = (idx & 127) << 2;
    const float* r0 = g + (size_t)b * 1536 + j4;
    f32x4 gi = *(const f32x4*)r0 + *(const f32x4*)(bp + j4);
    f32x4 gg = *(const f32x4*)(r0 + 512) + *(const f32x4*)(bp + 1024 + j4);
    f32x4 go = *(const f32x4*)(r0 + 1024) + *(const f32x4*)(bp + 1536 + j4);
    u16x4 h, l;
    float x[4];
#pragma unroll
    for (int u = 0; u < 4; ++u)
        x[u] = tanhf(expf(gi[u]) * tanhf(gg[u])) / (1.f + expf(-go[u]));
    h.x = f2bf(x[0]); h.y = f2bf(x[1]); h.z = f2bf(x[2]); h.w = f2bf(x[3]);
    l.x = f2bf(x[0] - bf2f(h.x)); l.y = f2bf(x[1] - bf2f(h.y));
    l.z = f2bf(x[2] - bf2f(h.z)); l.w = f2bf(x[3] - bf2f(h.w));
    size_t o = (size_t)b * HID + j4;
    nts4(hhi + o, h);
    nts4(hlo + o, l);
}

// ---------------- mLSTM head math + layernorm (+optional fused final projection) ----------------
__global__ __launch_bounds__(512) void k_mlstm(
    const float* __restrict__ g0,
    const float* __restrict__ bq, const float* __restrict__ bk, const float* __restrict__ bv,
    const bf16* __restrict__ hinh, const bf16* __restrict__ hinl,
    const float* __restrict__ igw, const float* __restrict__ igb,
    const float* __restrict__ lng, const float* __restrict__ lnb,
    unsigned short* __restrict__ outh, unsigned short* __restrict__ outl,
    const float* __restrict__ opw, const float* __restrict__ opb, float* __restrict__ out)
{
    int b = blockIdx.x;
    int tid = threadIdx.x, head = tid >> 6, lane = tid & 63;

    const bf16*  hh = hinh + (size_t)b * HID;
    const float* wrow = igw + head * HID;
    float s = 0.f;
#pragma unroll
    for (int k = 0; k < 8; ++k) {
        int p = lane + 64 * k;
        s += wrow[p] * __bfloat162float(hh[p]);
    }
#pragma unroll
    for (int off = 32; off; off >>= 1) s += __shfl_xor(s, off);
    float ig = expf(s + igb[head]);

    const float* r0 = g0 + (size_t)b * 1536;
    float q  = r0[tid] + bq[tid];
    float kk = r0[512 + tid] + bk[tid];
    float v  = r0[1024 + tid] + bv[tid];
    float kq = kk * q, vq = v * q;
#pragma unroll
    for (int off = 32; off; off >>= 1) { kq += __shfl_xor(kq, off); vq += __shfl_xor(vq, off); }
    float den = ig * (vq + 1.0f) + 1e-6f;
    float hv  = v * (ig * kq) / den;

    __shared__ float red[16];
    __shared__ float red2[8];
    float s1 = hv, s2 = hv * hv;
#pragma unroll
    for (int off = 32; off; off >>= 1) { s1 += __shfl_xor(s1, off); s2 += __shfl_xor(s2, off); }
    if (lane == 0) { red[head] = s1; red[8 + head] = s2; }
    __syncthreads();
    float t1 = 0.f, t2 = 0.f;
#pragma unroll
    for (int h2 = 0; h2 < 8; ++h2) { t1 += red[h2]; t2 += red[8 + h2]; }
    float mu  = t1 * (1.f / 512.f);
    float var = t2 * (1.f / 512.f) - mu * mu;
    float o = (hv - mu) * rsqrtf(var + 1e-5f) * lng[tid] + lnb[tid];

    if (out) {   // fused final projection (layer 3)
        float po = o * opw[tid];
#pragma unroll
        for (int off = 32; off; off >>= 1) po += __shfl_xor(po, off);
        if (lane == 0) red2[head] = po;
        __syncthreads();
        if (tid == 0) {
            float tt = 0.f;
#pragma unroll
            for (int h2 = 0; h2 < 8; ++h2) tt += red2[h2];
            out[b] = tt + opb[0];
        }
    } else {
        unsigned short oh = f2bf(o);
        size_t p = (size_t)b * HID + tid;
        __builtin_nontemporal_store(oh, outh + p);
        __builtin_nontemporal_store(f2bf(o - bf2f(oh)), outl + p);
    }
}

extern "C" void kernel_launch(void* const* d_in, const int* in_sizes, int n_in,
                              void* d_out, int out_size, void* d_ws, size_t ws_size,
                              hipStream_t stream) {
    const float* V    = (const float*)d_in[0];
    const float* t    = (const float*)d_in[1];
    const float* ip_w = (const float*)d_in[2];
    const float* ip_b = (const float*)d_in[3];
    const float* op_w = (const float*)d_in[4];
    const float* op_b = (const float*)d_in[5];
    const float* s0_W = (const float*)d_in[6];
    const float* s0_b = (const float*)d_in[7];
    const float* s2_W = (const float*)d_in[9];
    const float* s2_b = (const float*)d_in[10];
    const float* m1_Wq = (const float*)d_in[12];
    const float* m1_Wk = (const float*)d_in[13];
    const float* m1_Wv = (const float*)d_in[14];
    const float* m1_bq = (const float*)d_in[15];
    const float* m1_bk = (const float*)d_in[16];
    const float* m1_bv = (const float*)d_in[17];
    const float* m1_igw = (const float*)d_in[18];
    const float* m1_igb = (const float*)d_in[19];
    const float* m1_lng = (const float*)d_in[22];
    const float* m1_lnb = (const float*)d_in[23];
    const float* m3_Wq = (const float*)d_in[24];
    const float* m3_Wk = (const float*)d_in[25];
    const float* m3_Wv = (const float*)d_in[26];
    const float* m3_bq = (const float*)d_in[27];
    const float* m3_bk = (const float*)d_in[28];
    const float* m3_bv = (const float*)d_in[29];
    const float* m3_igw = (const float*)d_in[30];
    const float* m3_igb = (const float*)d_in[31];
    const float* m3_lng = (const float*)d_in[34];
    const float* m3_lnb = (const float*)d_in[35];

    char* ws = (char*)d_ws;
    bf16* whi  = (bf16*)ws;
    bf16* wlo  = (bf16*)(ws + 7340032);
    bf16* hAhi = (bf16*)(ws + 14680064);
    bf16* hAlo = (bf16*)(ws + 16777216);
    bf16* hBhi = (bf16*)(ws + 18874368);
    bf16* hBlo = (bf16*)(ws + 20971520);
    float* gq  = (float*)(ws + 23068672);
    float* uV  = (float*)(ws + 35651584);
    float* uT  = uV + 1536;
    float* uC  = uT + 1536;

    CvtArgs ca;
    ca.src[0] = s2_W;
    ca.src[1] = m1_Wq; ca.src[2] = m1_Wk; ca.src[3] = m1_Wv;
    ca.src[4] = m3_Wq; ca.src[5] = m3_Wk; ca.src[6] = m3_Wv;
    k_prep<<<2944, 256, 0, stream>>>(ca, (unsigned short*)whi, (unsigned short*)wlo,
                                     s0_W, s0_b, ip_w, ip_b, uV, uT, uC);

    // layer 0: sLSTM via rank-2 trick (no GEMM)
    k_slstm0<<<1024, 256, 0, stream>>>(V, t, uV, uT, uC,
                                       (unsigned short*)hBhi, (unsigned short*)hBlo);
    // layer 1: mLSTM (fused q|k|v)
    k_gemm<<<192, 256, 0, stream>>>(hBhi, hBlo,
        whi + 2097152, whi + 2359296, whi + 2621440,
        wlo + 2097152, wlo + 2359296, wlo + 2621440, gq);
    k_mlstm<<<BATCH, 512, 0, stream>>>(gq, m1_bq, m1_bk, m1_bv, hBhi, hBlo,
                                       m1_igw, m1_igb, m1_lng, m1_lnb,
                                       (unsigned short*)hAhi, (unsigned short*)hAlo,
                                       nullptr, nullptr, nullptr);
    // layer 2: sLSTM
    k_gemm<<<192, 256, 0, stream>>>(hAhi, hAlo,
        whi + 1048576, whi + 1572864, whi + 1835008,
        wlo + 1048576, wlo + 1572864, wlo + 1835008, gq);
    k_slstm_act<<<1024, 256, 0, stream>>>(gq, s2_b, (unsigned short*)hBhi, (unsigned short*)hBlo);
    // layer 3: mLSTM + fused output projection
    k_gemm<<<192, 256, 0, stream>>>(hBhi, hBlo,
        whi + 2883584, whi + 3145728, whi + 3407872,
        wlo + 2883584, wlo + 3145728, wlo + 3407872, gq);
    k_mlstm<<<BATCH, 512, 0, stream>>>(gq, m3_bq, m3_bk, m3_bv, hBhi, hBlo,
                                       m3_igw, m3_igb, m3_lng, m3_lnb,
                                       nullptr, nullptr,
                                       op_w, op_b, (float*)d_out);
}

// Round 22
// 99.585 us; speedup vs baseline: 1.0854x; 1.0854x over previous
//
#include <hip/hip_runtime.h>
#include <hip/hip_bf16.h>

#define HID 512
#define BATCH 2048

typedef __bf16 bf16x8 __attribute__((ext_vector_type(8)));
typedef float f32x4 __attribute__((ext_vector_type(4)));
typedef float f32x16 __attribute__((ext_vector_type(16)));
typedef __hip_bfloat16 bf16;

__device__ inline unsigned short f2bf(float x) {
    bf16 h = __float2bfloat16(x);
    return __builtin_bit_cast(unsigned short, h);
}
__device__ inline float bf2f(unsigned short u) {
    return __bfloat162float(__builtin_bit_cast(bf16, u));
}

__device__ inline void gload16(const void* g, void* l) {
    __builtin_amdgcn_global_load_lds((const __attribute__((address_space(1))) void*)g,
                                     (__attribute__((address_space(3))) void*)l, 16, 0, 0);
}

// ---------------- prep: weight hi/lo split (s2, m1, m3) + layer-0 rank-2 GEMV ----------------
struct CvtArgs { const float* src[7]; };   // s2_W, m1 q/k/v, m3 q/k/v

__global__ void k_prep(CvtArgs a, unsigned short* __restrict__ hi, unsigned short* __restrict__ lo,
                       const float* __restrict__ s0W, const float* __restrict__ s0b,
                       const float* __restrict__ ipw, const float* __restrict__ ipb,
                       float* __restrict__ uV, float* __restrict__ uT, float* __restrict__ uC) {
    const int bid = blockIdx.x;
    if (bid < 2560) {   // cvt: 2,621,440 elems / 4 / 256
        int idx4 = (bid * 256 + threadIdx.x) << 2;
        int seg, off; size_t dst;
        if (idx4 < 1048576) { seg = 0; off = idx4; dst = 1048576 + idx4; }          // s2_W
        else { int r = idx4 - 1048576; seg = 1 + (r >> 18); off = r & 262143; dst = 2097152 + r; }
        f32x4 w = *(const f32x4*)(a.src[seg] + off);
        ushort4 h, l;
        h.x = f2bf(w[0]); h.y = f2bf(w[1]); h.z = f2bf(w[2]); h.w = f2bf(w[3]);
        l.x = f2bf(w[0] - bf2f(h.x)); l.y = f2bf(w[1] - bf2f(h.y));
        l.z = f2bf(w[2] - bf2f(h.z)); l.w = f2bf(w[3] - bf2f(h.w));
        *(ushort4*)(hi + dst) = h;
        *(ushort4*)(lo + dst) = l;
    } else {            // GEMV: 1536 gate rows (skip f-rows 512-1023), 4 waves/block
        const int w = threadIdx.x >> 6, lane = threadIdx.x & 63;
        const int r = (bid - 2560) * 4 + w;            // compact row 0..1535
        const int wr = r < 512 ? r : r + 512;          // W row (i / g / o segments)
        const float* Wp = s0W + (size_t)wr * HID + lane * 8;
        f32x4 wa = *(const f32x4*)Wp, wb = *(const f32x4*)(Wp + 4);
        const float* pw = ipw + lane * 16;             // [HID][2] interleaved
        f32x4 e0 = *(const f32x4*)pw,       e1 = *(const f32x4*)(pw + 4);
        f32x4 e2 = *(const f32x4*)(pw + 8), e3 = *(const f32x4*)(pw + 12);
        f32x4 ba = *(const f32x4*)(ipb + lane * 8), bb = *(const f32x4*)(ipb + lane * 8 + 4);
        float s0 = wa[0]*e0[0] + wa[1]*e0[2] + wa[2]*e1[0] + wa[3]*e1[2]
                 + wb[0]*e2[0] + wb[1]*e2[2] + wb[2]*e3[0] + wb[3]*e3[2];
        float s1 = wa[0]*e0[1] + wa[1]*e0[3] + wa[2]*e1[1] + wa[3]*e1[3]
                 + wb[0]*e2[1] + wb[1]*e2[3] + wb[2]*e3[1] + wb[3]*e3[3];
        float s2 = wa[0]*ba[0] + wa[1]*ba[1] + wa[2]*ba[2] + wa[3]*ba[3]
                 + wb[0]*bb[0] + wb[1]*bb[1] + wb[2]*bb[2] + wb[3]*bb[3];
#pragma unroll
        for (int off = 32; off; off >>= 1) {
            s0 += __shfl_xor(s0, off); s1 += __shfl_xor(s1, off); s2 += __shfl_xor(s2, off);
        }
        if (lane == 0) { uV[r] = s0; uT[r] = s1; uC[r] = s2 + s0b[wr]; }
    }
}

// ---------------- layer-0 sLSTM: gates from rank-2 GEMV result, fused activation ----------------
__global__ void k_slstm0(const float* __restrict__ V, const float* __restrict__ t,
                         const float* __restrict__ uV, const float* __restrict__ uT,
                         const float* __restrict__ uC,
                         unsigned short* __restrict__ hhi, unsigned short* __restrict__ hlo) {
    int idx = blockIdx.x * blockDim.x + threadIdx.x;   // B*HID/4
    int b = idx >> 7, j4 = (idx & 127) << 2;
    float vv = V[b], tt = t[b];
    f32x4 gi = vv * *(const f32x4*)(uV + j4)        + tt * *(const f32x4*)(uT + j4)        + *(const f32x4*)(uC + j4);
    f32x4 gg = vv * *(const f32x4*)(uV + 512 + j4)  + tt * *(const f32x4*)(uT + 512 + j4)  + *(const f32x4*)(uC + 512 + j4);
    f32x4 go = vv * *(const f32x4*)(uV + 1024 + j4) + tt * *(const f32x4*)(uT + 1024 + j4) + *(const f32x4*)(uC + 1024 + j4);
    ushort4 h, l;
    float x[4];
#pragma unroll
    for (int u = 0; u < 4; ++u)
        x[u] = tanhf(expf(gi[u]) * tanhf(gg[u])) / (1.f + expf(-go[u]));
    h.x = f2bf(x[0]); h.y = f2bf(x[1]); h.z = f2bf(x[2]); h.w = f2bf(x[3]);
    l.x = f2bf(x[0] - bf2f(h.x)); l.y = f2bf(x[1] - bf2f(h.y));
    l.z = f2bf(x[2] - bf2f(h.z)); l.w = f2bf(x[3] - bf2f(h.w));
    size_t o = (size_t)b * HID + j4;
    *(ushort4*)(hhi + o) = h;
    *(ushort4*)(hlo + o) = l;
}

// ---------------- native-K split-bf16 GEMM: BK=32, 16 steps, 3-buffer pipeline ----------------
// C[2048][1536] = Ah*Wh + Al*Wh + Ah*Wl over K=512.  Block 128x128, 4 waves.
// LDS buffer (32KB) = 32 chunks of 1KB; chunk c = (m<<3)+(rb<<1)+ks, m: 0=Ah,1=Al,2=Wh,3=Wl,
// rb=rowblock 0..3, ks=k-subgroup 0..1.  Chunk: lane l <-> row (l&31), k = 16*ks + 8*(l>>5)..+8.
// Wave w stages matrix w (8 gload16/step).  24 MFMAs per barrier (2 ks x 12).
// vmcnt: steady retire stage(t) -> vmcnt(8); t=15 -> vmcnt(0).  STAGE stops at t=13.
__global__ __launch_bounds__(256) void k_gemm(
    const bf16* __restrict__ Ahi, const bf16* __restrict__ Alo,
    const bf16* __restrict__ Wh0, const bf16* __restrict__ Wh1, const bf16* __restrict__ Wh2,
    const bf16* __restrict__ Wl0, const bf16* __restrict__ Wl1, const bf16* __restrict__ Wl2,
    float* __restrict__ C)
{
    __shared__ __align__(16) bf16 lds[3][16384];   // 96 KB
    const int tid = threadIdx.x, w = tid >> 6, lane = tid & 63;

    const int bid = blockIdx.x;                   // 192 blocks: 8 XCD x 24 slots
    const int xcd = bid & 7, slot = bid >> 3;
    const int m0 = (xcd * 2 + slot / 12) * 128;
    const int n0 = (slot % 12) * 128;
    const int nseg = n0 >> 9, nloc = n0 & 511;
    const bf16* Wh = nseg == 0 ? Wh0 : (nseg == 1 ? Wh1 : Wh2);
    const bf16* Wl = nseg == 0 ? Wl0 : (nseg == 1 ? Wl1 : Wl2);

    const bf16* msrc = (w == 0) ? Ahi : (w == 1) ? Alo : (w == 2) ? Wh : Wl;
    const int rowbase = (w < 2) ? m0 : nloc;
    const size_t srow = (size_t)(rowbase + (lane & 31)) * HID + ((lane >> 5) << 3);

    auto STAGE = [&](int t) {
        bf16* db = &lds[t % 3][0] + (w << 12) + (lane << 3);   // chunk base (m=w, rb=0, ks=0)
        const bf16* gp = msrc + srow + (t << 5);
#pragma unroll
        for (int rb = 0; rb < 4; ++rb)
#pragma unroll
            for (int ks = 0; ks < 2; ++ks)
                gload16(gp + (size_t)(rb << 5) * HID + (ks << 4),
                        db + (((rb << 1) + ks) << 9));
    };

    const int wm = w >> 1, wn = w & 1;
    const int la = lane << 3;
    f32x16 acc00 = {}, acc01 = {}, acc10 = {}, acc11 = {};

    STAGE(0);
    STAGE(1);
    for (int t = 0; t < 16; ++t) {
        if (t < 15)
            asm volatile("s_waitcnt vmcnt(8) lgkmcnt(0)\n\ts_barrier" ::: "memory");
        else
            asm volatile("s_waitcnt vmcnt(0) lgkmcnt(0)\n\ts_barrier" ::: "memory");
        if (t < 14) STAGE(t + 2);   // writes buf (t+2)%3 = (t-1)%3: reads drained above
        const bf16* lb = &lds[t % 3][0];
#pragma unroll
        for (int ks = 0; ks < 2; ++ks) {
            bf16x8 ah0 = *(const bf16x8*)(lb + ((((2*wm    ) << 1) + ks) << 9) + la);
            bf16x8 ah1 = *(const bf16x8*)(lb + ((((2*wm + 1) << 1) + ks) << 9) + la);
            bf16x8 al0 = *(const bf16x8*)(lb + ((8 + ((2*wm    ) << 1) + ks) << 9) + la);
            bf16x8 al1 = *(const bf16x8*)(lb + ((8 + ((2*wm + 1) << 1) + ks) << 9) + la);
            bf16x8 wh0 = *(const bf16x8*)(lb + ((16 + ((2*wn    ) << 1) + ks) << 9) + la);
            bf16x8 wh1 = *(const bf16x8*)(lb + ((16 + ((2*wn + 1) << 1) + ks) << 9) + la);
            bf16x8 wl0 = *(const bf16x8*)(lb + ((24 + ((2*wn    ) << 1) + ks) << 9) + la);
            bf16x8 wl1 = *(const bf16x8*)(lb + ((24 + ((2*wn + 1) << 1) + ks) << 9) + la);
            __builtin_amdgcn_s_setprio(1);
            acc00 = __builtin_amdgcn_mfma_f32_32x32x16_bf16(ah0, wh0, acc00, 0, 0, 0);
            acc01 = __builtin_amdgcn_mfma_f32_32x32x16_bf16(ah0, wh1, acc01, 0, 0, 0);
            acc10 = __builtin_amdgcn_mfma_f32_32x32x16_bf16(ah1, wh0, acc10, 0, 0, 0);
            acc11 = __builtin_amdgcn_mfma_f32_32x32x16_bf16(ah1, wh1, acc11, 0, 0, 0);
            acc00 = __builtin_amdgcn_mfma_f32_32x32x16_bf16(al0, wh0, acc00, 0, 0, 0);
            acc01 = __builtin_amdgcn_mfma_f32_32x32x16_bf16(al0, wh1, acc01, 0, 0, 0);
            acc10 = __builtin_amdgcn_mfma_f32_32x32x16_bf16(al1, wh0, acc10, 0, 0, 0);
            acc11 = __builtin_amdgcn_mfma_f32_32x32x16_bf16(al1, wh1, acc11, 0, 0, 0);
            acc00 = __builtin_amdgcn_mfma_f32_32x32x16_bf16(ah0, wl0, acc00, 0, 0, 0);
            acc01 = __builtin_amdgcn_mfma_f32_32x32x16_bf16(ah0, wl1, acc01, 0, 0, 0);
            acc10 = __builtin_amdgcn_mfma_f32_32x32x16_bf16(ah1, wl0, acc10, 0, 0, 0);
            acc11 = __builtin_amdgcn_mfma_f32_32x32x16_bf16(ah1, wl1, acc11, 0, 0, 0);
            __builtin_amdgcn_s_setprio(0);
        }
    }

    // epilogue: D layout col = lane&31, row = (rr&3) + 8*(rr>>2) + 4*(lane>>5)
    const f32x16* accs[2][2] = { { &acc00, &acc01 }, { &acc10, &acc11 } };
#pragma unroll
    for (int fi = 0; fi < 2; ++fi)
#pragma unroll
        for (int fj = 0; fj < 2; ++fj) {
            const f32x16& ac = *accs[fi][fj];
            const int col = n0 + ((2 * wn + fj) << 5) + (lane & 31);
            const int rbase = m0 + ((2 * wm + fi) << 5) + ((lane >> 5) << 2);
#pragma unroll
            for (int rr = 0; rr < 16; ++rr) {
                int row = rbase + (rr & 3) + ((rr >> 2) << 3);
                C[(size_t)row * 1536 + col] = ac[rr];
            }
        }
}

// ---------------- sLSTM activation (layer 2): + bias, h = sigm(o)*tanh(exp(i)*tanh(g)) ----------------
__global__ void k_slstm_act(const float* __restrict__ g, const float* __restrict__ bp,
                            unsigned short* __restrict__ hhi, unsigned short* __restrict__ hlo) {
    int idx = blockIdx.x * blockDim.x + threadIdx.x;
    int b = idx >> 7, j4 = (idx & 127) << 2;
    const float* r0 = g + (size_t)b * 1536 + j4;
    f32x4 gi = *(const f32x4*)r0 + *(const f32x4*)(bp + j4);
    f32x4 gg = *(const f32x4*)(r0 + 512) + *(const f32x4*)(bp + 1024 + j4);
    f32x4 go = *(const f32x4*)(r0 + 1024) + *(const f32x4*)(bp + 1536 + j4);
    ushort4 h, l;
    float x[4];
#pragma unroll
    for (int u = 0; u < 4; ++u)
        x[u] = tanhf(expf(gi[u]) * tanhf(gg[u])) / (1.f + expf(-go[u]));
    h.x = f2bf(x[0]); h.y = f2bf(x[1]); h.z = f2bf(x[2]); h.w = f2bf(x[3]);
    l.x = f2bf(x[0] - bf2f(h.x)); l.y = f2bf(x[1] - bf2f(h.y));
    l.z = f2bf(x[2] - bf2f(h.z)); l.w = f2bf(x[3] - bf2f(h.w));
    size_t o = (size_t)b * HID + j4;
    *(ushort4*)(hhi + o) = h;
    *(ushort4*)(hlo + o) = l;
}

// ---------------- mLSTM head math + layernorm (+optional fused final projection) ----------------
__global__ __launch_bounds__(512) void k_mlstm(
    const float* __restrict__ g0,
    const float* __restrict__ bq, const float* __restrict__ bk, const float* __restrict__ bv,
    const bf16* __restrict__ hinh, const bf16* __restrict__ hinl,
    const float* __restrict__ igw, const float* __restrict__ igb,
    const float* __restrict__ lng, const float* __restrict__ lnb,
    unsigned short* __restrict__ outh, unsigned short* __restrict__ outl,
    const float* __restrict__ opw, const float* __restrict__ opb, float* __restrict__ out)
{
    int b = blockIdx.x;
    int tid = threadIdx.x, head = tid >> 6, lane = tid & 63;

    const bf16*  hh = hinh + (size_t)b * HID;
    const float* wrow = igw + head * HID;
    float s = 0.f;
#pragma unroll
    for (int k = 0; k < 8; ++k) {
        int p = lane + 64 * k;
        s += wrow[p] * __bfloat162float(hh[p]);
    }
#pragma unroll
    for (int off = 32; off; off >>= 1) s += __shfl_xor(s, off);
    float ig = expf(s + igb[head]);

    const float* r0 = g0 + (size_t)b * 1536;
    float q  = r0[tid] + bq[tid];
    float kk = r0[512 + tid] + bk[tid];
    float v  = r0[1024 + tid] + bv[tid];
    float kq = kk * q, vq = v * q;
#pragma unroll
    for (int off = 32; off; off >>= 1) { kq += __shfl_xor(kq, off); vq += __shfl_xor(vq, off); }
    float den = ig * (vq + 1.0f) + 1e-6f;
    float hv  = v * (ig * kq) / den;

    __shared__ float red[16];
    __shared__ float red2[8];
    float s1 = hv, s2 = hv * hv;
#pragma unroll
    for (int off = 32; off; off >>= 1) { s1 += __shfl_xor(s1, off); s2 += __shfl_xor(s2, off); }
    if (lane == 0) { red[head] = s1; red[8 + head] = s2; }
    __syncthreads();
    float t1 = 0.f, t2 = 0.f;
#pragma unroll
    for (int h2 = 0; h2 < 8; ++h2) { t1 += red[h2]; t2 += red[8 + h2]; }
    float mu  = t1 * (1.f / 512.f);
    float var = t2 * (1.f / 512.f) - mu * mu;
    float o = (hv - mu) * rsqrtf(var + 1e-5f) * lng[tid] + lnb[tid];

    if (out) {   // fused final projection (layer 3)
        float po = o * opw[tid];
#pragma unroll
        for (int off = 32; off; off >>= 1) po += __shfl_xor(po, off);
        if (lane == 0) red2[head] = po;
        __syncthreads();
        if (tid == 0) {
            float tt = 0.f;
#pragma unroll
            for (int h2 = 0; h2 < 8; ++h2) tt += red2[h2];
            out[b] = tt + opb[0];
        }
    } else {
        unsigned short oh = f2bf(o);
        size_t p = (size_t)b * HID + tid;
        outh[p] = oh;
        outl[p] = f2bf(o - bf2f(oh));
    }
}

extern "C" void kernel_launch(void* const* d_in, const int* in_sizes, int n_in,
                              void* d_out, int out_size, void* d_ws, size_t ws_size,
                              hipStream_t stream) {
    const float* V    = (const float*)d_in[0];
    const float* t    = (const float*)d_in[1];
    const float* ip_w = (const float*)d_in[2];
    const float* ip_b = (const float*)d_in[3];
    const float* op_w = (const float*)d_in[4];
    const float* op_b = (const float*)d_in[5];
    const float* s0_W = (const float*)d_in[6];
    const float* s0_b = (const float*)d_in[7];
    const float* s2_W = (const float*)d_in[9];
    const float* s2_b = (const float*)d_in[10];
    const float* m1_Wq = (const float*)d_in[12];
    const float* m1_Wk = (const float*)d_in[13];
    const float* m1_Wv = (const float*)d_in[14];
    const float* m1_bq = (const float*)d_in[15];
    const float* m1_bk = (const float*)d_in[16];
    const float* m1_bv = (const float*)d_in[17];
    const float* m1_igw = (const float*)d_in[18];
    const float* m1_igb = (const float*)d_in[19];
    const float* m1_lng = (const float*)d_in[22];
    const float* m1_lnb = (const float*)d_in[23];
    const float* m3_Wq = (const float*)d_in[24];
    const float* m3_Wk = (const float*)d_in[25];
    const float* m3_Wv = (const float*)d_in[26];
    const float* m3_bq = (const float*)d_in[27];
    const float* m3_bk = (const float*)d_in[28];
    const float* m3_bv = (const float*)d_in[29];
    const float* m3_igw = (const float*)d_in[30];
    const float* m3_igb = (const float*)d_in[31];
    const float* m3_lng = (const float*)d_in[34];
    const float* m3_lnb = (const float*)d_in[35];

    char* ws = (char*)d_ws;
    bf16* whi  = (bf16*)ws;
    bf16* wlo  = (bf16*)(ws + 7340032);
    bf16* hAhi = (bf16*)(ws + 14680064);
    bf16* hAlo = (bf16*)(ws + 16777216);
    bf16* hBhi = (bf16*)(ws + 18874368);
    bf16* hBlo = (bf16*)(ws + 20971520);
    float* gq  = (float*)(ws + 23068672);
    float* uV  = (float*)(ws + 35651584);
    float* uT  = uV + 1536;
    float* uC  = uT + 1536;

    CvtArgs ca;
    ca.src[0] = s2_W;
    ca.src[1] = m1_Wq; ca.src[2] = m1_Wk; ca.src[3] = m1_Wv;
    ca.src[4] = m3_Wq; ca.src[5] = m3_Wk; ca.src[6] = m3_Wv;
    k_prep<<<2944, 256, 0, stream>>>(ca, (unsigned short*)whi, (unsigned short*)wlo,
                                     s0_W, s0_b, ip_w, ip_b, uV, uT, uC);

    // layer 0: sLSTM via rank-2 trick (no GEMM)
    k_slstm0<<<1024, 256, 0, stream>>>(V, t, uV, uT, uC,
                                       (unsigned short*)hBhi, (unsigned short*)hBlo);
    // layer 1: mLSTM (fused q|k|v)
    k_gemm<<<192, 256, 0, stream>>>(hBhi, hBlo,
        whi + 2097152, whi + 2359296, whi + 2621440,
        wlo + 2097152, wlo + 2359296, wlo + 2621440, gq);
    k_mlstm<<<BATCH, 512, 0, stream>>>(gq, m1_bq, m1_bk, m1_bv, hBhi, hBlo,
                                       m1_igw, m1_igb, m1_lng, m1_lnb,
                                       (unsigned short*)hAhi, (unsigned short*)hAlo,
                                       nullptr, nullptr, nullptr);
    // layer 2: sLSTM
    k_gemm<<<192, 256, 0, stream>>>(hAhi, hAlo,
        whi + 1048576, whi + 1572864, whi + 1835008,
        wlo + 1048576, wlo + 1572864, wlo + 1835008, gq);
    k_slstm_act<<<1024, 256, 0, stream>>>(gq, s2_b, (unsigned short*)hBhi, (unsigned short*)hBlo);
    // layer 3: mLSTM + fused output projection
    k_gemm<<<192, 256, 0, stream>>>(hBhi, hBlo,
        whi + 2883584, whi + 3145728, whi + 3407872,
        wlo + 2883584, wlo + 3145728, wlo + 3407872, gq);
    k_mlstm<<<BATCH, 512, 0, stream>>>(gq, m3_bq, m3_bk, m3_bv, hBhi, hBlo,
                                       m3_igw, m3_igb, m3_lng, m3_lnb,
                                       nullptr, nullptr,
                                       op_w, op_b, (float*)d_out);
}